// Round 6
// baseline (778.685 us; speedup 1.0000x reference)
//
#include <hip/hip_runtime.h>
#include <hip/hip_cooperative_groups.h>

#define NEG 0.2f

namespace cg = cooperative_groups;

struct Args {
    const float* x; const int* srcI; const int* dstI; const float* edge_attr;
    const float* W; const float* W_edge; const float* att_src; const float* att_dst;
    const float* att_edge; const float* bias;
    float* wke; float* hbuf; float* a_src; float* a_dst;
    int* count; int* offs; int* cursor; int* bsum;
    float4* evec; float* out;
    int N; long long E;
};

__global__ __launch_bounds__(256, 4) void fused(Args a) {
    __shared__ float Wl[128 * 64];   // 32 KB; aliased by later phases
    __shared__ float xs[512];        // 2 KB;  aliased: ts (scan), wkes (pa)
    cg::grid_group grid = cg::this_grid();
    const int t   = threadIdx.x;
    const int NB  = gridDim.x;
    const long long gtid    = (long long)blockIdx.x * 256 + t;
    const long long gstride = (long long)NB * 256;
    const int N = a.N;
    const long long E = a.E;

    // ---- Phase 0: zero count, fold wke, node projection ----
    for (long long i = gtid; i < N; i += gstride) a.count[i] = 0;
    if (blockIdx.x == 0 && t < 128) {
        int hh = t >> 6, k = t & 63;
        float s = 0.f;
#pragma unroll
        for (int c = 0; c < 32; ++c)
            s += a.W_edge[k * 64 + hh * 32 + c] * a.att_edge[hh * 32 + c];
        a.wke[hh * 64 + k] = s;
    }
    {
        for (int i = t; i < 128 * 64; i += 256) Wl[i] = a.W[i];
        int col = t & 63;
        int nl  = t >> 6;
        float asw = a.att_src[col];
        float adw = a.att_dst[col];
        __syncthreads();
        int ngroups = (N + 63) / 64;
        for (int g = blockIdx.x; g < ngroups; g += NB) {
            int node0 = g * 64;
            for (int it = 0; it < 16; ++it) {
                int nb = node0 + it * 4;
                __syncthreads();
                for (int j = t; j < 512; j += 256) {
                    int nn = nb + (j >> 7);
                    int k  = j & 127;
                    xs[j] = (nn < N) ? fmaxf(a.x[(size_t)nn * 128 + k], 0.f) : 0.f;
                }
                __syncthreads();
                int n = nb + nl;
                float acc = 0.f;
#pragma unroll 8
                for (int k = 0; k < 128; ++k)
                    acc = fmaf(xs[nl * 128 + k], Wl[k * 64 + col], acc);
                float vs = acc * asw, vd = acc * adw;
#pragma unroll
                for (int m = 1; m <= 16; m <<= 1) {
                    vs += __shfl_xor(vs, m, 64);
                    vd += __shfl_xor(vd, m, 64);
                }
                if (n < N) {
                    a.hbuf[(size_t)n * 64 + col] = acc;
                    if ((col & 31) == 0) {
                        int hh = col >> 5;
                        a.a_src[n * 2 + hh] = vs;
                        a.a_dst[n * 2 + hh] = vd;
                    }
                }
            }
        }
    }
    grid.sync();   // S1

    // ---- Phase 1: in-degree histogram ----
    for (long long i = gtid; i < E; i += gstride)
        atomicAdd(&a.count[a.dstI[i]], 1);
    grid.sync();   // S2

    // ---- Phase 2a: per-chunk exclusive scan (chunk = PB elements per block) ----
    const int PB = (N + NB - 1) / NB;   // <= 256 for NB >= 196
    int* ts = (int*)xs;
    {
        int base = blockIdx.x * PB;
        int v = 0;
        if (t < PB && base + t < N) v = a.count[base + t];
        ts[t] = v;
        __syncthreads();
        for (int off = 1; off < 256; off <<= 1) {
            int y = (t >= off) ? ts[t - off] : 0;
            __syncthreads();
            ts[t] += y;
            __syncthreads();
        }
        int incl = ts[t];
        if (t < PB && base + t < N) a.offs[base + t] = incl - v;
        if (t == 255) a.bsum[blockIdx.x] = ts[255];
    }
    grid.sync();   // S3

    // ---- Phase 2b: block 0 scans the NB chunk totals (exclusive) ----
    if (blockIdx.x == 0) {
        int K = (NB + 255) / 256;   // <= 4
        int vloc[4]; int s = 0;
        for (int i = 0; i < K; ++i) {
            int idx = t * K + i;
            vloc[i] = (idx < NB) ? a.bsum[idx] : 0;
            s += vloc[i];
        }
        ts[t] = s;
        __syncthreads();
        for (int off = 1; off < 256; off <<= 1) {
            int y = (t >= off) ? ts[t - off] : 0;
            __syncthreads();
            ts[t] += y;
            __syncthreads();
        }
        int run = ts[t] - s;
        for (int i = 0; i < K; ++i) {
            int idx = t * K + i;
            if (idx < NB) a.bsum[idx] = run;
            run += vloc[i];
        }
    }
    grid.sync();   // S4

    // ---- Phase 2c: globalize offsets, init cursor ----
    for (long long i = gtid; i < N; i += gstride) {
        int o = a.offs[i] + a.bsum[(int)(i / PB)];
        a.offs[i] = o;
        a.cursor[i] = o;
    }
    grid.sync();   // S5

    // ---- Phase 3: edge sweep (a_edge dot) + CSR scatter ----
    {
        float* wkes = xs;
        if (t < 128) wkes[t] = a.wke[t];
        __syncthreads();
        for (long long e = gtid; e < E; e += gstride) {
            const float4* row = (const float4*)(a.edge_attr + e * 64);
            float pa0 = 0.f, pa1 = 0.f;
#pragma unroll
            for (int k = 0; k < 16; ++k) {
                float4 ea = row[k];
                float4 wa = *(const float4*)(wkes + k * 4);
                float4 wb = *(const float4*)(wkes + 64 + k * 4);
                pa0 += ea.x * wa.x + ea.y * wa.y + ea.z * wa.z + ea.w * wa.w;
                pa1 += ea.x * wb.x + ea.y * wb.y + ea.z * wb.z + ea.w * wb.w;
            }
            int s = a.srcI[e], d = a.dstI[e];
            int pos = atomicAdd(&a.cursor[d], 1);
            a.evec[pos] = make_float4(pa0, pa1, __int_as_float(s), 0.f);
        }
    }
    grid.sync();   // S6

    // ---- Phase 4: per-node aggregation (wave per node, 4-way edge-parallel) ----
    {
        int lane = t & 63;
        int sub = lane & 15;
        int grp = lane >> 4;
        int ngroups = (N + 3) / 4;
        for (int g = blockIdx.x; g < ngroups; g += NB) {
            int n = g * 4 + (t >> 6);
            if (n >= N) continue;   // wave-uniform
            int cnt  = a.count[n];
            int base = a.offs[n];
            float ad0 = a.a_dst[n * 2 + 0], ad1 = a.a_dst[n * 2 + 1];
            float accx = 0.f, accy = 0.f, accz = 0.f, accw = 0.f;
            float den0 = 0.f, den1 = 0.f, sae0 = 0.f, sae1 = 0.f;
            if (cnt > 0) {
                int last = cnt - 1;
                float4 evA = a.evec[base + (grp < cnt ? grp : last)];
                float4 evB = a.evec[base + (grp + 4 < cnt ? grp + 4 : last)];
                int sA = __float_as_int(evA.z);
                int sB = __float_as_int(evB.z);
                float2 asA = *(const float2*)(a.a_src + 2 * (size_t)sA);
                float4 hvA = *(const float4*)(a.hbuf + (size_t)sA * 64 + sub * 4);
                for (int j = grp; j < cnt; j += 4) {
                    int jc = j + 8 < cnt ? j + 8 : last;
                    float4 evC = a.evec[base + jc];
                    float2 asB = *(const float2*)(a.a_src + 2 * (size_t)sB);
                    float4 hvB = *(const float4*)(a.hbuf + (size_t)sB * 64 + sub * 4);
                    float l0 = asA.x + ad0 + evA.x; l0 = l0 > 0.f ? l0 : NEG * l0;
                    float l1 = asA.y + ad1 + evA.y; l1 = l1 > 0.f ? l1 : NEG * l1;
                    float q0 = __expf(l0), q1 = __expf(l1);
                    float q = (sub < 8) ? q0 : q1;
                    accx = fmaf(q, hvA.x, accx);
                    accy = fmaf(q, hvA.y, accy);
                    accz = fmaf(q, hvA.z, accz);
                    accw = fmaf(q, hvA.w, accw);
                    den0 += q0; den1 += q1;
                    sae0 += evA.x; sae1 += evA.y;
                    evA = evB; sA = sB; asA = asB; hvA = hvB;
                    evB = evC; sB = __float_as_int(evC.z);
                }
            }
#define RED2(v) { v += __shfl_xor(v, 16, 64); v += __shfl_xor(v, 32, 64); }
            RED2(accx) RED2(accy) RED2(accz) RED2(accw)
            RED2(den0) RED2(den1) RED2(sae0) RED2(sae1)
#undef RED2
            float dg = (cnt > 0) ? (float)cnt : 1.f;
            float as0 = a.a_src[n * 2 + 0], as1 = a.a_src[n * 2 + 1];
            float l0 = as0 + ad0 + sae0 / dg; l0 = l0 > 0.f ? l0 : NEG * l0;
            float l1 = as1 + ad1 + sae1 / dg; l1 = l1 > 0.f ? l1 : NEG * l1;
            float pl0 = __expf(l0), pl1 = __expf(l1);
            const float4 hn = *(const float4*)(a.hbuf + (size_t)n * 64 + sub * 4);
            float pl  = (sub < 8) ? pl0 : pl1;
            float den = ((sub < 8) ? den0 + pl0 : den1 + pl1) + 1e-16f;
            const float4 bv = *(const float4*)(a.bias + sub * 4);
            if (grp == 0) {
                float4 o;
                o.x = (accx + pl * hn.x) / den + bv.x;
                o.y = (accy + pl * hn.y) / den + bv.y;
                o.z = (accz + pl * hn.z) / den + bv.z;
                o.w = (accw + pl * hn.w) / den + bv.w;
                *(float4*)(a.out + (size_t)n * 64 + sub * 4) = o;
            }
        }
    }
}

extern "C" void kernel_launch(void* const* d_in, const int* in_sizes, int n_in,
                              void* d_out, int out_size, void* d_ws, size_t ws_size,
                              hipStream_t stream) {
    Args a;
    a.x         = (const float*)d_in[0];
    const int* ei = (const int*)d_in[1];
    a.edge_attr = (const float*)d_in[2];
    a.W         = (const float*)d_in[3];
    a.W_edge    = (const float*)d_in[4];
    a.att_src   = (const float*)d_in[5];
    a.att_dst   = (const float*)d_in[6];
    a.att_edge  = (const float*)d_in[7];
    a.bias      = (const float*)d_in[8];
    a.N = in_sizes[0] / 128;
    a.E = in_sizes[1] / 2;
    a.srcI = ei;
    a.dstI = ei + a.E;
    a.out  = (float*)d_out;

    char* ws = (char*)d_ws;
    a.evec   = (float4*)ws;             ws += (size_t)a.E * 16;
    a.wke    = (float*)ws;              ws += 128 * 4;
    a.hbuf   = (float*)ws;              ws += (size_t)a.N * 64 * 4;
    a.a_src  = (float*)ws;              ws += (size_t)a.N * 2 * 4;
    a.a_dst  = (float*)ws;              ws += (size_t)a.N * 2 * 4;
    a.count  = (int*)ws;                ws += (size_t)a.N * 4;
    a.offs   = (int*)ws;                ws += (size_t)a.N * 4;
    a.cursor = (int*)ws;                ws += (size_t)a.N * 4;
    a.bsum   = (int*)ws;                ws += 2048 * 4;

    int maxb = 0;
    if (hipOccupancyMaxActiveBlocksPerMultiprocessor(
            &maxb, reinterpret_cast<const void*>(&fused), 256, 0) != hipSuccess || maxb <= 0)
        maxb = 4;
    int NB = maxb * 256;            // 256 CUs on MI355X
    if (NB > 1024) NB = 1024;

    void* params[] = { &a };
    hipLaunchCooperativeKernel(reinterpret_cast<const void*>(&fused),
                               dim3(NB), dim3(256), params, 0, stream);
}

// Round 7
// 295.519 us; speedup vs baseline: 2.6350x; 2.6350x over previous
//
#include <hip/hip_runtime.h>

#define NEG 0.2f

// Zero-fill for count (hipMemsetAsync small-fill path is pathological ~1GB/s).
__global__ __launch_bounds__(256) void k_zero(int* __restrict__ p, int n) {
    int i = blockIdx.x * 256 + threadIdx.x;
    if (i < n) p[i] = 0;
}

// h = relu(x) @ W, register-blocked 4x4: each thread owns 4 nodes x 4 cols.
// Per k: 2 x ds_read_b128 -> 16 FMAs (vs 2 reads per 1 FMA before).
// 128 threads/block, 32 nodes/block. LDS 51KB -> 3 blocks/CU.
__global__ __launch_bounds__(128) void k_node(
    const float* __restrict__ x, const float* __restrict__ W,
    const float* __restrict__ att_src, const float* __restrict__ att_dst,
    float* __restrict__ hbuf, float* __restrict__ a_src, float* __restrict__ a_dst, int N) {
    __shared__ float xs[128 * 36];   // [k][node], row stride 36 floats (16B aligned)
    __shared__ float Wl[128 * 64];   // [k][col]
    const int t  = threadIdx.x;
    const int tn = t & 7;            // node group (4 nodes)
    const int tc = t >> 3;           // col group (4 cols), 0..15
    const int node0 = blockIdx.x * 32;

    // stage W: direct copy (row-major [k][col])
    for (int j = t; j < 128 * 64; j += 128) Wl[j] = W[j];
    // stage x tile transposed: xs[k][n] = relu(x[node0+n][k])
    for (int j = t; j < 32 * 128; j += 128) {
        int n = j >> 7, k = j & 127;
        int nn = node0 + n;
        xs[k * 36 + n] = (nn < N) ? fmaxf(x[(size_t)nn * 128 + k], 0.f) : 0.f;
    }
    __syncthreads();

    float4 acc[4] = {{0,0,0,0},{0,0,0,0},{0,0,0,0},{0,0,0,0}};  // [n] over cols
#pragma unroll 8
    for (int k = 0; k < 128; ++k) {
        const float4 xv = *(const float4*)(xs + k * 36 + 4 * tn);
        const float4 wv = *(const float4*)(Wl + k * 64 + 4 * tc);
        acc[0].x = fmaf(xv.x, wv.x, acc[0].x); acc[0].y = fmaf(xv.x, wv.y, acc[0].y);
        acc[0].z = fmaf(xv.x, wv.z, acc[0].z); acc[0].w = fmaf(xv.x, wv.w, acc[0].w);
        acc[1].x = fmaf(xv.y, wv.x, acc[1].x); acc[1].y = fmaf(xv.y, wv.y, acc[1].y);
        acc[1].z = fmaf(xv.y, wv.z, acc[1].z); acc[1].w = fmaf(xv.y, wv.w, acc[1].w);
        acc[2].x = fmaf(xv.z, wv.x, acc[2].x); acc[2].y = fmaf(xv.z, wv.y, acc[2].y);
        acc[2].z = fmaf(xv.z, wv.z, acc[2].z); acc[2].w = fmaf(xv.z, wv.w, acc[2].w);
        acc[3].x = fmaf(xv.w, wv.x, acc[3].x); acc[3].y = fmaf(xv.w, wv.y, acc[3].y);
        acc[3].z = fmaf(xv.w, wv.z, acc[3].z); acc[3].w = fmaf(xv.w, wv.w, acc[3].w);
    }

    // write h
#pragma unroll
    for (int n = 0; n < 4; ++n) {
        int nn = node0 + 4 * tn + n;
        if (nn < N) *(float4*)(hbuf + (size_t)nn * 64 + 4 * tc) = acc[n];
    }

    // a_src/a_dst: per-thread partial dot over its 4 cols, butterfly over tc (lane bits 3,4,5)
    const float4 as4 = *(const float4*)(att_src + 4 * tc);
    const float4 ad4 = *(const float4*)(att_dst + 4 * tc);
    int head = (t >= 64) ? 1 : 0;    // wave0: tc 0..7 (head0), wave1: tc 8..15 (head1)
#pragma unroll
    for (int n = 0; n < 4; ++n) {
        float vs = acc[n].x * as4.x + acc[n].y * as4.y + acc[n].z * as4.z + acc[n].w * as4.w;
        float vd = acc[n].x * ad4.x + acc[n].y * ad4.y + acc[n].z * ad4.z + acc[n].w * ad4.w;
#pragma unroll
        for (int m = 8; m <= 32; m <<= 1) {
            vs += __shfl_xor(vs, m, 64);
            vd += __shfl_xor(vd, m, 64);
        }
        int nn = node0 + 4 * tn + n;
        if ((t & 63) < 8 && nn < N) {
            a_src[nn * 2 + head] = vs;
            a_dst[nn * 2 + head] = vd;
        }
    }
}

// In-degree histogram (1 int atomic/edge) + wke fold (block 0).
// wke[h*64+k] = sum_c W_edge[k][h*32+c] * att_edge[h][c]
__global__ __launch_bounds__(256) void k_hist(
    const int* __restrict__ dstI, int* __restrict__ count, long long E,
    const float* __restrict__ W_edge, const float* __restrict__ att_edge,
    float* __restrict__ wke) {
    if (blockIdx.x == 0 && threadIdx.x < 128) {
        int hh = threadIdx.x >> 6;
        int k  = threadIdx.x & 63;
        float s = 0.f;
#pragma unroll
        for (int c = 0; c < 32; ++c)
            s += W_edge[k * 64 + hh * 32 + c] * att_edge[hh * 32 + c];
        wke[hh * 64 + k] = s;
    }
    long long i0 = (long long)blockIdx.x * 256 + threadIdx.x;
    long long stride = (long long)gridDim.x * 256;
    for (long long i = i0; i < E; i += stride)
        atomicAdd(&count[dstI[i]], 1);
}

// Exclusive scan, 1024 elements per block (256 thr x 4).
__global__ __launch_bounds__(256) void k_scan1(const int* __restrict__ cnt, int* __restrict__ offs,
                                               int* __restrict__ bsum, int N) {
    __shared__ int ts[256];
    int t = threadIdx.x, blk = blockIdx.x;
    int base = blk * 1024 + t * 4;
    int v[4], s = 0;
#pragma unroll
    for (int i = 0; i < 4; ++i) {
        int idx = base + i;
        v[i] = (idx < N) ? cnt[idx] : 0;
        s += v[i];
    }
    ts[t] = s;
    __syncthreads();
    for (int off = 1; off < 256; off <<= 1) {
        int y = (t >= off) ? ts[t - off] : 0;
        __syncthreads();
        ts[t] += y;
        __syncthreads();
    }
    int run = ts[t] - s;   // exclusive prefix of this thread's chunk
#pragma unroll
    for (int i = 0; i < 4; ++i) {
        int idx = base + i;
        if (idx < N) offs[idx] = run;
        run += v[i];
    }
    if (t == 255) bsum[blk] = ts[255];
}

// Single-wave shuffle scan over block sums (nb <= 64).
__global__ void k_scan2(int* __restrict__ bsum, int nb) {
    int t = threadIdx.x;   // 64 threads
    int orig = (t < nb) ? bsum[t] : 0;
    int v = orig;
#pragma unroll
    for (int off = 1; off < 64; off <<= 1) {
        int y = __shfl_up(v, off, 64);
        if (t >= off) v += y;
    }
    if (t < nb) bsum[t] = v - orig;   // exclusive
}

__global__ void k_scan3(int* __restrict__ offs, const int* __restrict__ bsum,
                        int* __restrict__ cursor, int N) {
    int idx = blockIdx.x * 256 + threadIdx.x;
    if (idx < N) {
        int o = offs[idx] + bsum[idx >> 10];
        offs[idx] = o;
        cursor[idx] = o;
    }
}

// Edge sweep: ONE edge per thread, wke broadcast from LDS, CSR scatter.
__global__ __launch_bounds__(256) void k_pa(
    const float* __restrict__ edge_attr, const int* __restrict__ srcI,
    const int* __restrict__ dstI, const float* __restrict__ wke,
    int* __restrict__ cursor, float4* __restrict__ evec, long long E) {
    __shared__ float wkes[128];
    if (threadIdx.x < 128) wkes[threadIdx.x] = wke[threadIdx.x];
    __syncthreads();
    long long i0 = (long long)blockIdx.x * 256 + threadIdx.x;
    long long stride = (long long)gridDim.x * 256;
    for (long long e = i0; e < E; e += stride) {
        const float4* row = (const float4*)(edge_attr + e * 64);
        float pa0 = 0.f, pa1 = 0.f;
#pragma unroll
        for (int k = 0; k < 16; ++k) {
            float4 ea = row[k];
            float4 wa = *(const float4*)(wkes + k * 4);
            float4 wb = *(const float4*)(wkes + 64 + k * 4);
            pa0 += ea.x * wa.x + ea.y * wa.y + ea.z * wa.z + ea.w * wa.w;
            pa1 += ea.x * wb.x + ea.y * wb.y + ea.z * wb.z + ea.w * wb.w;
        }
        int s = srcI[e], d = dstI[e];
        int pos = atomicAdd(&cursor[d], 1);
        evec[pos] = make_float4(pa0, pa1, __int_as_float(s), 0.f);
    }
}

// Per-node aggregation: 64 lanes/node, 4-way edge-parallel, software-pipelined.
__global__ __launch_bounds__(256) void k_agg(
    const float4* __restrict__ evec, const int* __restrict__ offs,
    const int* __restrict__ count, const float* __restrict__ a_src,
    const float* __restrict__ a_dst, const float* __restrict__ hbuf,
    const float* __restrict__ bias, float* __restrict__ out, int N) {
    int t = threadIdx.x;
    int lane = t & 63;
    int sub = lane & 15;
    int grp = lane >> 4;
    int n = blockIdx.x * 4 + (t >> 6);
    if (n >= N) return;
    int cnt  = count[n];
    int base = offs[n];
    float ad0 = a_dst[n * 2 + 0], ad1 = a_dst[n * 2 + 1];
    float accx = 0.f, accy = 0.f, accz = 0.f, accw = 0.f;
    float den0 = 0.f, den1 = 0.f, sae0 = 0.f, sae1 = 0.f;

    if (cnt > 0) {
        int last = cnt - 1;
        float4 evA = evec[base + (grp < cnt ? grp : last)];
        float4 evB = evec[base + (grp + 4 < cnt ? grp + 4 : last)];
        int sA = __float_as_int(evA.z);
        int sB = __float_as_int(evB.z);
        float2 asA = *(const float2*)(a_src + 2 * (size_t)sA);
        float4 hvA = *(const float4*)(hbuf + (size_t)sA * 64 + sub * 4);
        for (int j = grp; j < cnt; j += 4) {
            int jc = j + 8 < cnt ? j + 8 : last;
            float4 evC = evec[base + jc];
            float2 asB = *(const float2*)(a_src + 2 * (size_t)sB);
            float4 hvB = *(const float4*)(hbuf + (size_t)sB * 64 + sub * 4);
            float l0 = asA.x + ad0 + evA.x; l0 = l0 > 0.f ? l0 : NEG * l0;
            float l1 = asA.y + ad1 + evA.y; l1 = l1 > 0.f ? l1 : NEG * l1;
            float q0 = __expf(l0), q1 = __expf(l1);
            float q = (sub < 8) ? q0 : q1;
            accx = fmaf(q, hvA.x, accx);
            accy = fmaf(q, hvA.y, accy);
            accz = fmaf(q, hvA.z, accz);
            accw = fmaf(q, hvA.w, accw);
            den0 += q0; den1 += q1;
            sae0 += evA.x; sae1 += evA.y;
            evA = evB; sA = sB; asA = asB; hvA = hvB;
            evB = evC; sB = __float_as_int(evC.z);
        }
    }
#define RED2(v) { v += __shfl_xor(v, 16, 64); v += __shfl_xor(v, 32, 64); }
    RED2(accx) RED2(accy) RED2(accz) RED2(accw)
    RED2(den0) RED2(den1) RED2(sae0) RED2(sae1)
#undef RED2

    float dg = (cnt > 0) ? (float)cnt : 1.f;
    float as0 = a_src[n * 2 + 0], as1 = a_src[n * 2 + 1];
    float l0 = as0 + ad0 + sae0 / dg; l0 = l0 > 0.f ? l0 : NEG * l0;
    float l1 = as1 + ad1 + sae1 / dg; l1 = l1 > 0.f ? l1 : NEG * l1;
    float pl0 = __expf(l0), pl1 = __expf(l1);
    const float4 hn = *(const float4*)(hbuf + (size_t)n * 64 + sub * 4);
    float pl  = (sub < 8) ? pl0 : pl1;
    float den = ((sub < 8) ? den0 + pl0 : den1 + pl1) + 1e-16f;
    const float4 bv = *(const float4*)(bias + sub * 4);
    if (grp == 0) {
        float4 o;
        o.x = (accx + pl * hn.x) / den + bv.x;
        o.y = (accy + pl * hn.y) / den + bv.y;
        o.z = (accz + pl * hn.z) / den + bv.z;
        o.w = (accw + pl * hn.w) / den + bv.w;
        *(float4*)(out + (size_t)n * 64 + sub * 4) = o;
    }
}

extern "C" void kernel_launch(void* const* d_in, const int* in_sizes, int n_in,
                              void* d_out, int out_size, void* d_ws, size_t ws_size,
                              hipStream_t stream) {
    const float* x         = (const float*)d_in[0];
    const int*   ei        = (const int*)d_in[1];
    const float* edge_attr = (const float*)d_in[2];
    const float* W         = (const float*)d_in[3];
    const float* W_edge    = (const float*)d_in[4];
    const float* att_src   = (const float*)d_in[5];
    const float* att_dst   = (const float*)d_in[6];
    const float* att_edge  = (const float*)d_in[7];
    const float* bias      = (const float*)d_in[8];

    int N = in_sizes[0] / 128;
    long long E = in_sizes[1] / 2;
    const int* srcI = ei;
    const int* dstI = ei + E;

    // Workspace layout (16B-aligned first)
    char* ws = (char*)d_ws;
    float4* evec  = (float4*)ws;                      ws += (size_t)E * 16;
    float* wke    = (float*)ws;                       ws += 128 * 4;
    float* hbuf   = (float*)ws;                       ws += (size_t)N * 64 * 4;
    float* a_src  = (float*)ws;                       ws += (size_t)N * 2 * 4;
    float* a_dst  = (float*)ws;                       ws += (size_t)N * 2 * 4;
    int*   count  = (int*)ws;                         ws += (size_t)N * 4;
    int*   offs   = (int*)ws;                         ws += (size_t)N * 4;
    int*   cursor = (int*)ws;                         ws += (size_t)N * 4;
    int*   bsum   = (int*)ws;                         ws += 64 * 4;

    k_zero<<<(N + 255) / 256, 256, 0, stream>>>(count, N);
    k_node<<<(N + 31) / 32, 128, 0, stream>>>(x, W, att_src, att_dst, hbuf, a_src, a_dst, N);
    k_hist<<<2048, 256, 0, stream>>>(dstI, count, E, W_edge, att_edge, wke);

    int nb = (N + 1023) / 1024;
    k_scan1<<<nb, 256, 0, stream>>>(count, offs, bsum, N);
    k_scan2<<<1, 64, 0, stream>>>(bsum, nb);
    k_scan3<<<(N + 255) / 256, 256, 0, stream>>>(offs, bsum, cursor, N);

    k_pa<<<2048, 256, 0, stream>>>(edge_attr, srcI, dstI, wke, cursor, evec, E);

    k_agg<<<(N + 3) / 4, 256, 0, stream>>>(evec, offs, count, a_src, a_dst, hbuf, bias,
                                           (float*)d_out, N);
}